// Round 15
// baseline (30.865 us; speedup 1.0000x reference)
//
#include <hip/hip_runtime.h>
#include <hip/hip_bf16.h>
#include <cstddef>

#define B_ 8
#define C_ 2048
#define E_ 256
#define H_ 64
#define T_ 512
#define NA 4
#define KAPPA 0.9f
#define LOG2_KAPPA (-0.15200309344504997f)   // log2(0.9)
#define KAPPA_T 3.73302e-24f                 // 0.9^512

typedef __attribute__((ext_vector_type(8))) short bf16x8;
typedef __attribute__((ext_vector_type(4))) float f32x4;

__device__ inline unsigned short f2bfu(float x) {
    unsigned u = __builtin_bit_cast(unsigned, x);
    u += 0x7fff + ((u >> 16) & 1);   // RNE
    return (unsigned short)(u >> 16);
}
__device__ inline short f2bf(float x) { return (short)f2bfu(x); }
__device__ inline float bf2f(unsigned short u) {
    return __builtin_bit_cast(float, (unsigned)u << 16);
}
__device__ inline unsigned pack2bf(float lo, float hi) {
    return (unsigned)f2bfu(lo) | ((unsigned)f2bfu(hi) << 16);
}

#define GLOAD_LDS16(gp, lp)                                                    \
    __builtin_amdgcn_global_load_lds(                                          \
        (const __attribute__((address_space(1))) void*)(gp),                   \
        (__attribute__((address_space(3))) void*)(lp), 16, 0, 0)

// ---- prep: blocks 0-11 W transpose f32 -> SWIZZLED bf16 wt; 12-19 s_tab ----
// wt layout (per mat, 32768B): byte(d,k) = d*512 + ((2k) ^ ((d&7)<<4)).
__global__ __launch_bounds__(256) void prep_kernel(
    const float* __restrict__ w_q, const float* __restrict__ w_k,
    const float* __restrict__ w_v, char* __restrict__ wt,
    const unsigned char* __restrict__ raw, int* __restrict__ s_tab)
{
    const int t = threadIdx.x;
    if (blockIdx.x < 12) {
        const int mat = blockIdx.x >> 2;
        const int k0  = (blockIdx.x & 3) * 64;
        const float* W = (mat == 0) ? w_q : (mat == 1) ? w_k : w_v;
        char* wm = wt + (size_t)mat * 32768;
        __shared__ float tile[64][67];
#pragma unroll
        for (int pass = 0; pass < 16; ++pass) {
            int idx = pass * 256 + t;
            int r = idx >> 6, c = idx & 63;
            tile[r][c] = W[(size_t)(k0 + r) * H_ + c];
        }
        __syncthreads();
#pragma unroll
        for (int pass = 0; pass < 16; ++pass) {
            int idx = pass * 256 + t;
            int d = idx >> 6, c = idx & 63;
            int byte = (d << 9) + ((((k0 + c) << 1)) ^ ((d & 7) << 4));
            *(short*)(wm + byte) = f2bf(tile[c][d]);
        }
    } else {
        const int b    = blockIdx.x - 12;
        const int lane = t & 63;
        const int w    = t >> 6;
        __shared__ int f;
        __shared__ unsigned long long msk[8];
        if (t == 0) f = 0;
        __syncthreads();
        {   // layout detection: bool(1B) vs int32(4B LE 0/1)
            const uint4* dp = (const uint4*)raw;
            unsigned acc = 0;
#pragma unroll
            for (int i = 0; i < 4; ++i) {
                uint4 v = dp[t + 256 * i];     // 16KB = B_*C_ bytes
                acc |= (v.x | v.y | v.z | v.w) & 0xFFFFFF00u;
            }
            if (acc) f = 1;
        }
        __syncthreads();
        const int stride = f ? 1 : 4;
        const unsigned char* drow = raw + (size_t)b * C_ * stride;
#pragma unroll
        for (int cc = 0; cc < 2; ++cc) {
            const int c = 2 * w + cc;
            const int n = c * 64 + lane;
            unsigned long long m = __ballot(drow[(size_t)(4 * n) * stride] != 0);
            if (lane == 0) msk[c] = m;
        }
        __syncthreads();
#pragma unroll
        for (int cc = 0; cc < 2; ++cc) {
            const int c = 2 * w + cc;
            const int n = c * 64 + lane;
            unsigned long long lowmask =
                (lane == 63) ? ~0ULL : ((1ULL << (lane + 1)) - 1ULL);
            unsigned long long m_le = msk[c] & lowmask;
            int s = -1;
            if (m_le) {
                s = c * 64 + (63 - __builtin_clzll(m_le));
            } else {
                for (int c2 = c - 1; c2 >= 0; --c2)
                    if (msk[c2]) { s = c2 * 64 + (63 - __builtin_clzll(msk[c2])); break; }
            }
            s_tab[b * T_ + n] = s;
        }
    }
}

// ---------------- Projection GEMM via MFMA ----------------------------------
// ALL A-loads (16 x f32x4 = full 256B row slice) issued before the barrier,
// alongside the 8 global_load_lds for Wt: ONE latency drain per wave instead
// of 8 serialized round-trips (r14 theory). K-loop is pure LDS+cvt+MFMA.
__global__ __launch_bounds__(256) void proj_mfma(
    const float* __restrict__ key_in, const float* __restrict__ query,
    const float* __restrict__ value, const char* __restrict__ wt,
    unsigned short* __restrict__ qp, unsigned short* __restrict__ kp,
    unsigned short* __restrict__ vp)
{
    const int mat = blockIdx.y;
    const float* A; unsigned short* O16;
    if (mat == 0)      { A = query;  O16 = qp; }
    else if (mat == 1) { A = key_in; O16 = kp; }
    else               { A = value;  O16 = vp; }

    __shared__ __align__(16) char Wt[64 * 512];   // linear 32KB, swizzled image

    const int t    = threadIdx.x;
    const int b    = blockIdx.x & 7;
    const int rb   = blockIdx.x >> 3;
    const int row0 = b * C_ + rb * 64;
    const int lane = t & 63;
    const int mt   = t >> 6;
    const int lr   = lane & 15;
    const int lg   = lane >> 4;
    const int swz  = (lr & 7) << 4;

    const char* wsrc = wt + (size_t)mat * 32768;
#pragma unroll
    for (int pass = 0; pass < 8; ++pass)
        GLOAD_LDS16(wsrc + pass * 4096 + t * 16, Wt + pass * 4096 + t * 16);

    const float* arow = &A[(size_t)(row0 + mt * 16 + lr) * E_ + lg * 8];

    // issue the thread's entire A slice (8 kc x 2 x f32x4) back-to-back
    f32x4 x[8][2];
#pragma unroll
    for (int kc = 0; kc < 8; ++kc) {
        x[kc][0] = *(const f32x4*)(arow + kc * 32);
        x[kc][1] = *(const f32x4*)(arow + kc * 32 + 4);
    }
    __syncthreads();    // drains gload_lds; A loads complete on first use

    f32x4 acc[4] = {};
#pragma unroll
    for (int kc = 0; kc < 8; ++kc) {
        bf16x8 af;
        af[0] = f2bf(x[kc][0][0]); af[1] = f2bf(x[kc][0][1]);
        af[2] = f2bf(x[kc][0][2]); af[3] = f2bf(x[kc][0][3]);
        af[4] = f2bf(x[kc][1][0]); af[5] = f2bf(x[kc][1][1]);
        af[6] = f2bf(x[kc][1][2]); af[7] = f2bf(x[kc][1][3]);
#pragma unroll
        for (int nt = 0; nt < 4; ++nt) {
            bf16x8 bfrag = *(const bf16x8*)&Wt[((nt * 16 + lr) << 9) +
                                               ((kc * 64 + lg * 16) ^ swz)];
            acc[nt] = __builtin_amdgcn_mfma_f32_16x16x32_bf16(af, bfrag, acc[nt], 0, 0, 0);
        }
    }

    // packed bf16 epilogue: lane pair (lr, lr^1) packs adjacent cols into
    // dwords; even lane stores rows 0-1, odd lane rows 2-3 -> dword stores.
    const int odd   = lr & 1;
    const int rbase = row0 + mt * 16 + lg * 4;
#pragma unroll
    for (int nt = 0; nt < 4; ++nt) {
        const int cp = nt * 16 + (lr & ~1);
        float x0_ = acc[nt][0], x1_ = acc[nt][1], x2_ = acc[nt][2], x3_ = acc[nt][3];
        float y0 = __shfl_xor(x0_, 1), y1 = __shfl_xor(x1_, 1);
        float y2 = __shfl_xor(x2_, 1), y3 = __shfl_xor(x3_, 1);
        if (!odd) {
            *(unsigned*)&O16[(size_t)(rbase + 0) * H_ + cp] = pack2bf(x0_, y0);
            *(unsigned*)&O16[(size_t)(rbase + 1) * H_ + cp] = pack2bf(x1_, y1);
        } else {
            *(unsigned*)&O16[(size_t)(rbase + 2) * H_ + cp] = pack2bf(y2, x2_);
            *(unsigned*)&O16[(size_t)(rbase + 3) * H_ + cp] = pack2bf(y3, x3_);
        }
    }
}

// ---------------- out0 + next_h, wave-per-unit, s from table ----------------
// blocks 0..1023 -> out0: b = bid&7 (XCD pin), n = (bid>>3)*4 + wave.
// blocks 1024..1151 -> next_h: b = j&7, h = (j>>3)*4 + wave.
__global__ __launch_bounds__(256) void out_kernel(
    const unsigned short* __restrict__ qp, const unsigned short* __restrict__ kp,
    const unsigned short* __restrict__ vp, const float* __restrict__ hs,
    const int* __restrict__ s_tab,
    float* __restrict__ out0, float* __restrict__ outh)
{
    const int t    = threadIdx.x;
    const int lane = t & 63;
    const int w    = t >> 6;
    const int bid  = blockIdx.x;

    if (bid < 1024) {
        const int b = bid & 7;
        const int n = (bid >> 3) * 4 + w;
        const int a = lane >> 4;
        const int g = lane & 15;

        const int st = s_tab[b * T_ + n];
        const int s  = (st < 0) ? 0 : st;

        const unsigned short* kb = kp + (size_t)b * C_ * H_;
        const unsigned short* vb = vp + (size_t)b * C_ * H_;
        ushort4 qu = *(const ushort4*)&qp[((size_t)b * C_ + 4 * n + a) * H_ + 4 * g];
        f32x4 q4 = { bf2f(qu.x), bf2f(qu.y), bf2f(qu.z), bf2f(qu.w) };

        f32x4 acc = {};
        // diagonal timestep: decay 1, causal mask ma <= a
#pragma unroll
        for (int ma = 0; ma < NA; ++ma) {
            const int m = 4 * n + ma;
            ushort4 ku = *(const ushort4*)&kb[(size_t)m * H_ + 4 * g];
            float p = q4[0] * bf2f(ku.x) + q4[1] * bf2f(ku.y)
                    + q4[2] * bf2f(ku.z) + q4[3] * bf2f(ku.w);
            p += __shfl_xor(p, 1); p += __shfl_xor(p, 2);
            p += __shfl_xor(p, 4); p += __shfl_xor(p, 8);
            if (ma <= a) {
                ushort4 vu = *(const ushort4*)&vb[(size_t)m * H_ + 4 * g];
                acc[0] += p * bf2f(vu.x); acc[1] += p * bf2f(vu.y);
                acc[2] += p * bf2f(vu.z); acc[3] += p * bf2f(vu.w);
            }
        }
        // earlier timesteps in segment
        float decay = KAPPA;
        for (int mt = n - 1; mt >= s; --mt) {
#pragma unroll
            for (int ma = 0; ma < NA; ++ma) {
                const int m = 4 * mt + ma;
                ushort4 ku = *(const ushort4*)&kb[(size_t)m * H_ + 4 * g];
                float p = q4[0] * bf2f(ku.x) + q4[1] * bf2f(ku.y)
                        + q4[2] * bf2f(ku.z) + q4[3] * bf2f(ku.w);
                p += __shfl_xor(p, 1); p += __shfl_xor(p, 2);
                p += __shfl_xor(p, 4); p += __shfl_xor(p, 8);
                p *= decay;
                ushort4 vu = *(const ushort4*)&vb[(size_t)m * H_ + 4 * g];
                acc[0] += p * bf2f(vu.x); acc[1] += p * bf2f(vu.y);
                acc[2] += p * bf2f(vu.z); acc[3] += p * bf2f(vu.w);
            }
            decay *= KAPPA;
        }
        // cross term (xi != 0 iff no done in [0, n] <=> st < 0)
        if (st < 0) {
            const float xi = exp2f(LOG2_KAPPA * (float)(n + 1));
            const float* hsb = hs + (size_t)b * H_ * H_;
            f32x4 cacc = {};
#pragma unroll
            for (int h = 0; h < H_; ++h) {
                float qh = __shfl(q4[h & 3], (a << 4) + (h >> 2));
                f32x4 h4 = *(const f32x4*)&hsb[h * H_ + 4 * g];
                cacc[0] += qh * h4[0]; cacc[1] += qh * h4[1];
                cacc[2] += qh * h4[2]; cacc[3] += qh * h4[3];
            }
            acc[0] += xi * cacc[0]; acc[1] += xi * cacc[1];
            acc[2] += xi * cacc[2]; acc[3] += xi * cacc[3];
        }
        *(f32x4*)&out0[((size_t)b * C_ + 4 * n + a) * H_ + 4 * g] = acc;
    } else {
        const int j = bid - 1024;            // [0,128)
        const int b = j & 7;
        const int h = (j >> 3) * 4 + w;      // [0,64)
        const int d = lane;

        const int st = s_tab[b * T_ + (T_ - 1)];
        const int s  = (st < 0) ? 0 : st;

        const unsigned short* kb = kp + (size_t)b * C_ * H_;
        const unsigned short* vb = vp + (size_t)b * C_ * H_;
        float acc = 0.f, wdec = 1.f;
        for (int mt = T_ - 1; mt >= s; --mt) {
#pragma unroll
            for (int ma = 0; ma < NA; ++ma) {
                const int m = 4 * mt + ma;
                acc += wdec * bf2f(kb[(size_t)m * H_ + h]) *
                              bf2f(vb[(size_t)m * H_ + d]);
            }
            wdec *= KAPPA;
        }
        if (st < 0)
            acc += hs[((size_t)b * H_ + h) * H_ + d] * KAPPA_T;
        outh[((size_t)b * H_ + h) * H_ + d] = acc;
    }
}

extern "C" void kernel_launch(void* const* d_in, const int* in_sizes, int n_in,
                              void* d_out, int out_size, void* d_ws, size_t ws_size,
                              hipStream_t stream)
{
    const float* key_in = (const float*)d_in[0];
    const float* query  = (const float*)d_in[1];
    const float* value  = (const float*)d_in[2];
    const float* hstate = (const float*)d_in[3];
    const unsigned char* dones = (const unsigned char*)d_in[4];
    const float* w_q = (const float*)d_in[5];
    const float* w_k = (const float*)d_in[6];
    const float* w_v = (const float*)d_in[7];

    unsigned short* qp = (unsigned short*)d_ws;
    unsigned short* kp = qp + (size_t)B_ * C_ * H_;
    unsigned short* vp = kp + (size_t)B_ * C_ * H_;
    char*           wt = (char*)(vp + (size_t)B_ * C_ * H_);
    int*         s_tab = (int*)(wt + 3 * 32768);

    prep_kernel<<<20, 256, 0, stream>>>(w_q, w_k, w_v, wt, dones, s_tab);
    dim3 pgrid(B_ * C_ / 64, 3);
    proj_mfma<<<pgrid, 256, 0, stream>>>(key_in, query, value, wt, qp, kp, vp);
    out_kernel<<<1024 + 128, 256, 0, stream>>>(
        qp, kp, vp, hstate, s_tab,
        (float*)d_out, (float*)d_out + (size_t)B_ * C_ * H_);
}

// Round 17
// 29.431 us; speedup vs baseline: 1.0487x; 1.0487x over previous
//
#include <hip/hip_runtime.h>
#include <hip/hip_bf16.h>
#include <cstddef>

#define B_ 8
#define C_ 2048
#define E_ 256
#define H_ 64
#define T_ 512
#define NA 4
#define KAPPA 0.9f
#define LOG2_KAPPA (-0.15200309344504997f)   // log2(0.9)
#define KAPPA_T 3.73302e-24f                 // 0.9^512

typedef __attribute__((ext_vector_type(8))) short bf16x8;
typedef __attribute__((ext_vector_type(4))) float f32x4;
typedef __attribute__((ext_vector_type(4))) unsigned u32x4;

__device__ inline unsigned short f2bfu(float x) {
    unsigned u = __builtin_bit_cast(unsigned, x);
    u += 0x7fff + ((u >> 16) & 1);   // RNE
    return (unsigned short)(u >> 16);
}
__device__ inline short f2bf(float x) { return (short)f2bfu(x); }
__device__ inline float bf2f(unsigned short u) {
    return __builtin_bit_cast(float, (unsigned)u << 16);
}
__device__ inline unsigned pack2bf(float lo, float hi) {
    return (unsigned)f2bfu(lo) | ((unsigned)f2bfu(hi) << 16);
}
// packed RNE cvt: lowers to v_cvt_pk_bf16_f32 (1 VALU op / 2 elems).
// memcpy instead of bit_cast: __hip_bfloat162 is not trivially copyable.
__device__ inline unsigned cvtpk(float a, float b) {
    __hip_bfloat162 h = __float22bfloat162_rn(float2{a, b});
    unsigned r;
    __builtin_memcpy(&r, &h, sizeof(r));
    return r;
}

#define GLOAD_LDS16(gp, lp)                                                    \
    __builtin_amdgcn_global_load_lds(                                          \
        (const __attribute__((address_space(1))) void*)(gp),                   \
        (__attribute__((address_space(3))) void*)(lp), 16, 0, 0)

// ---- prep: blocks 0-11 W transpose f32 -> SWIZZLED bf16 wt; 12-19 s_tab ----
// wt layout (per mat, 32768B): byte(d,k) = d*512 + ((2k) ^ ((d&7)<<4)).
__global__ __launch_bounds__(256) void prep_kernel(
    const float* __restrict__ w_q, const float* __restrict__ w_k,
    const float* __restrict__ w_v, char* __restrict__ wt,
    const unsigned char* __restrict__ raw, int* __restrict__ s_tab)
{
    const int t = threadIdx.x;
    if (blockIdx.x < 12) {
        const int mat = blockIdx.x >> 2;
        const int k0  = (blockIdx.x & 3) * 64;
        const float* W = (mat == 0) ? w_q : (mat == 1) ? w_k : w_v;
        char* wm = wt + (size_t)mat * 32768;
        __shared__ float tile[64][67];
#pragma unroll
        for (int pass = 0; pass < 16; ++pass) {
            int idx = pass * 256 + t;
            int r = idx >> 6, c = idx & 63;
            tile[r][c] = W[(size_t)(k0 + r) * H_ + c];
        }
        __syncthreads();
#pragma unroll
        for (int pass = 0; pass < 16; ++pass) {
            int idx = pass * 256 + t;
            int d = idx >> 6, c = idx & 63;
            int byte = (d << 9) + ((((k0 + c) << 1)) ^ ((d & 7) << 4));
            *(short*)(wm + byte) = f2bf(tile[c][d]);
        }
    } else {
        const int b    = blockIdx.x - 12;
        const int lane = t & 63;
        const int w    = t >> 6;
        __shared__ int f;
        __shared__ unsigned long long msk[8];
        if (t == 0) f = 0;
        __syncthreads();
        {   // layout detection: bool(1B) vs int32(4B LE 0/1)
            const uint4* dp = (const uint4*)raw;
            unsigned acc = 0;
#pragma unroll
            for (int i = 0; i < 4; ++i) {
                uint4 v = dp[t + 256 * i];     // 16KB = B_*C_ bytes
                acc |= (v.x | v.y | v.z | v.w) & 0xFFFFFF00u;
            }
            if (acc) f = 1;
        }
        __syncthreads();
        const int stride = f ? 1 : 4;
        const unsigned char* drow = raw + (size_t)b * C_ * stride;
#pragma unroll
        for (int cc = 0; cc < 2; ++cc) {
            const int c = 2 * w + cc;
            const int n = c * 64 + lane;
            unsigned long long m = __ballot(drow[(size_t)(4 * n) * stride] != 0);
            if (lane == 0) msk[c] = m;
        }
        __syncthreads();
#pragma unroll
        for (int cc = 0; cc < 2; ++cc) {
            const int c = 2 * w + cc;
            const int n = c * 64 + lane;
            unsigned long long lowmask =
                (lane == 63) ? ~0ULL : ((1ULL << (lane + 1)) - 1ULL);
            unsigned long long m_le = msk[c] & lowmask;
            int s = -1;
            if (m_le) {
                s = c * 64 + (63 - __builtin_clzll(m_le));
            } else {
                for (int c2 = c - 1; c2 >= 0; --c2)
                    if (msk[c2]) { s = c2 * 64 + (63 - __builtin_clzll(msk[c2])); break; }
            }
            s_tab[b * T_ + n] = s;
        }
    }
}

// ---------------- Projection GEMM via MFMA ----------------------------------
// r14 structure (rolling 1-ahead A prefetch) + packed v_cvt_pk_bf16_f32 for
// the A-fragment conversion (8 VALU/kc instead of ~64 - r15 theory).
__global__ __launch_bounds__(256) void proj_mfma(
    const float* __restrict__ key_in, const float* __restrict__ query,
    const float* __restrict__ value, const char* __restrict__ wt,
    unsigned short* __restrict__ qp, unsigned short* __restrict__ kp,
    unsigned short* __restrict__ vp)
{
    const int mat = blockIdx.y;
    const float* A; unsigned short* O16;
    if (mat == 0)      { A = query;  O16 = qp; }
    else if (mat == 1) { A = key_in; O16 = kp; }
    else               { A = value;  O16 = vp; }

    __shared__ __align__(16) char Wt[64 * 512];   // linear 32KB, swizzled image

    const int t    = threadIdx.x;
    const int b    = blockIdx.x & 7;
    const int rb   = blockIdx.x >> 3;
    const int row0 = b * C_ + rb * 64;
    const int lane = t & 63;
    const int mt   = t >> 6;
    const int lr   = lane & 15;
    const int lg   = lane >> 4;
    const int swz  = (lr & 7) << 4;

    const char* wsrc = wt + (size_t)mat * 32768;
#pragma unroll
    for (int pass = 0; pass < 8; ++pass)
        GLOAD_LDS16(wsrc + pass * 4096 + t * 16, Wt + pass * 4096 + t * 16);

    const float* arow = &A[(size_t)(row0 + mt * 16 + lr) * E_ + lg * 8];

    // prefetch kc=0 A while staging drains at the barrier
    f32x4 x0 = *(const f32x4*)(arow);
    f32x4 x1 = *(const f32x4*)(arow + 4);
    __syncthreads();

    f32x4 acc[4] = {};
#pragma unroll
    for (int kc = 0; kc < 8; ++kc) {
        f32x4 n0, n1;
        if (kc < 7) {
            n0 = *(const f32x4*)(arow + (kc + 1) * 32);
            n1 = *(const f32x4*)(arow + (kc + 1) * 32 + 4);
        }
        u32x4 afu = { cvtpk(x0[0], x0[1]), cvtpk(x0[2], x0[3]),
                      cvtpk(x1[0], x1[1]), cvtpk(x1[2], x1[3]) };
        bf16x8 af = __builtin_bit_cast(bf16x8, afu);
#pragma unroll
        for (int nt = 0; nt < 4; ++nt) {
            bf16x8 bfrag = *(const bf16x8*)&Wt[((nt * 16 + lr) << 9) +
                                               ((kc * 64 + lg * 16) ^ swz)];
            acc[nt] = __builtin_amdgcn_mfma_f32_16x16x32_bf16(af, bfrag, acc[nt], 0, 0, 0);
        }
        x0 = n0; x1 = n1;
    }

    // packed bf16 epilogue: lane pair (lr, lr^1) packs adjacent cols into
    // dwords; even lane stores rows 0-1, odd lane rows 2-3 -> dword stores.
    const int odd   = lr & 1;
    const int rbase = row0 + mt * 16 + lg * 4;
#pragma unroll
    for (int nt = 0; nt < 4; ++nt) {
        const int cp = nt * 16 + (lr & ~1);
        float x0_ = acc[nt][0], x1_ = acc[nt][1], x2_ = acc[nt][2], x3_ = acc[nt][3];
        float y0 = __shfl_xor(x0_, 1), y1 = __shfl_xor(x1_, 1);
        float y2 = __shfl_xor(x2_, 1), y3 = __shfl_xor(x3_, 1);
        if (!odd) {
            *(unsigned*)&O16[(size_t)(rbase + 0) * H_ + cp] = pack2bf(x0_, y0);
            *(unsigned*)&O16[(size_t)(rbase + 1) * H_ + cp] = pack2bf(x1_, y1);
        } else {
            *(unsigned*)&O16[(size_t)(rbase + 2) * H_ + cp] = pack2bf(y2, x2_);
            *(unsigned*)&O16[(size_t)(rbase + 3) * H_ + cp] = pack2bf(y3, x3_);
        }
    }
}

// ---------------- out0 + next_h, wave-per-unit, s from table ----------------
// blocks 0..1023 -> out0: b = bid&7 (XCD pin), n = (bid>>3)*4 + wave.
// blocks 1024..1151 -> next_h: b = j&7, h = (j>>3)*4 + wave.
__global__ __launch_bounds__(256) void out_kernel(
    const unsigned short* __restrict__ qp, const unsigned short* __restrict__ kp,
    const unsigned short* __restrict__ vp, const float* __restrict__ hs,
    const int* __restrict__ s_tab,
    float* __restrict__ out0, float* __restrict__ outh)
{
    const int t    = threadIdx.x;
    const int lane = t & 63;
    const int w    = t >> 6;
    const int bid  = blockIdx.x;

    if (bid < 1024) {
        const int b = bid & 7;
        const int n = (bid >> 3) * 4 + w;
        const int a = lane >> 4;
        const int g = lane & 15;

        const int st = s_tab[b * T_ + n];
        const int s  = (st < 0) ? 0 : st;

        const unsigned short* kb = kp + (size_t)b * C_ * H_;
        const unsigned short* vb = vp + (size_t)b * C_ * H_;
        ushort4 qu = *(const ushort4*)&qp[((size_t)b * C_ + 4 * n + a) * H_ + 4 * g];
        f32x4 q4 = { bf2f(qu.x), bf2f(qu.y), bf2f(qu.z), bf2f(qu.w) };

        f32x4 acc = {};
        // diagonal timestep: decay 1, causal mask ma <= a
#pragma unroll
        for (int ma = 0; ma < NA; ++ma) {
            const int m = 4 * n + ma;
            ushort4 ku = *(const ushort4*)&kb[(size_t)m * H_ + 4 * g];
            float p = q4[0] * bf2f(ku.x) + q4[1] * bf2f(ku.y)
                    + q4[2] * bf2f(ku.z) + q4[3] * bf2f(ku.w);
            p += __shfl_xor(p, 1); p += __shfl_xor(p, 2);
            p += __shfl_xor(p, 4); p += __shfl_xor(p, 8);
            if (ma <= a) {
                ushort4 vu = *(const ushort4*)&vb[(size_t)m * H_ + 4 * g];
                acc[0] += p * bf2f(vu.x); acc[1] += p * bf2f(vu.y);
                acc[2] += p * bf2f(vu.z); acc[3] += p * bf2f(vu.w);
            }
        }
        // earlier timesteps in segment
        float decay = KAPPA;
        for (int mt = n - 1; mt >= s; --mt) {
#pragma unroll
            for (int ma = 0; ma < NA; ++ma) {
                const int m = 4 * mt + ma;
                ushort4 ku = *(const ushort4*)&kb[(size_t)m * H_ + 4 * g];
                float p = q4[0] * bf2f(ku.x) + q4[1] * bf2f(ku.y)
                        + q4[2] * bf2f(ku.z) + q4[3] * bf2f(ku.w);
                p += __shfl_xor(p, 1); p += __shfl_xor(p, 2);
                p += __shfl_xor(p, 4); p += __shfl_xor(p, 8);
                p *= decay;
                ushort4 vu = *(const ushort4*)&vb[(size_t)m * H_ + 4 * g];
                acc[0] += p * bf2f(vu.x); acc[1] += p * bf2f(vu.y);
                acc[2] += p * bf2f(vu.z); acc[3] += p * bf2f(vu.w);
            }
            decay *= KAPPA;
        }
        // cross term (xi != 0 iff no done in [0, n] <=> st < 0)
        if (st < 0) {
            const float xi = exp2f(LOG2_KAPPA * (float)(n + 1));
            const float* hsb = hs + (size_t)b * H_ * H_;
            f32x4 cacc = {};
#pragma unroll
            for (int h = 0; h < H_; ++h) {
                float qh = __shfl(q4[h & 3], (a << 4) + (h >> 2));
                f32x4 h4 = *(const f32x4*)&hsb[h * H_ + 4 * g];
                cacc[0] += qh * h4[0]; cacc[1] += qh * h4[1];
                cacc[2] += qh * h4[2]; cacc[3] += qh * h4[3];
            }
            acc[0] += xi * cacc[0]; acc[1] += xi * cacc[1];
            acc[2] += xi * cacc[2]; acc[3] += xi * cacc[3];
        }
        *(f32x4*)&out0[((size_t)b * C_ + 4 * n + a) * H_ + 4 * g] = acc;
    } else {
        const int j = bid - 1024;            // [0,128)
        const int b = j & 7;
        const int h = (j >> 3) * 4 + w;      // [0,64)
        const int d = lane;

        const int st = s_tab[b * T_ + (T_ - 1)];
        const int s  = (st < 0) ? 0 : st;

        const unsigned short* kb = kp + (size_t)b * C_ * H_;
        const unsigned short* vb = vp + (size_t)b * C_ * H_;
        float acc = 0.f, wdec = 1.f;
        for (int mt = T_ - 1; mt >= s; --mt) {
#pragma unroll
            for (int ma = 0; ma < NA; ++ma) {
                const int m = 4 * mt + ma;
                acc += wdec * bf2f(kb[(size_t)m * H_ + h]) *
                              bf2f(vb[(size_t)m * H_ + d]);
            }
            wdec *= KAPPA;
        }
        if (st < 0)
            acc += hs[((size_t)b * H_ + h) * H_ + d] * KAPPA_T;
        outh[((size_t)b * H_ + h) * H_ + d] = acc;
    }
}

extern "C" void kernel_launch(void* const* d_in, const int* in_sizes, int n_in,
                              void* d_out, int out_size, void* d_ws, size_t ws_size,
                              hipStream_t stream)
{
    const float* key_in = (const float*)d_in[0];
    const float* query  = (const float*)d_in[1];
    const float* value  = (const float*)d_in[2];
    const float* hstate = (const float*)d_in[3];
    const unsigned char* dones = (const unsigned char*)d_in[4];
    const float* w_q = (const float*)d_in[5];
    const float* w_k = (const float*)d_in[6];
    const float* w_v = (const float*)d_in[7];

    unsigned short* qp = (unsigned short*)d_ws;
    unsigned short* kp = qp + (size_t)B_ * C_ * H_;
    unsigned short* vp = kp + (size_t)B_ * C_ * H_;
    char*           wt = (char*)(vp + (size_t)B_ * C_ * H_);
    int*         s_tab = (int*)(wt + 3 * 32768);

    prep_kernel<<<20, 256, 0, stream>>>(w_q, w_k, w_v, wt, dones, s_tab);
    dim3 pgrid(B_ * C_ / 64, 3);
    proj_mfma<<<pgrid, 256, 0, stream>>>(key_in, query, value, wt, qp, kp, vp);
    out_kernel<<<1024 + 128, 256, 0, stream>>>(
        qp, kp, vp, hstate, s_tab,
        (float*)d_out, (float*)d_out + (size_t)B_ * C_ * H_);
}

// Round 18
// 26.154 us; speedup vs baseline: 1.1801x; 1.1253x over previous
//
#include <hip/hip_runtime.h>
#include <hip/hip_bf16.h>
#include <cstddef>

#define B_ 8
#define C_ 2048
#define E_ 256
#define H_ 64
#define T_ 512
#define NA 4
#define KAPPA 0.9f
#define LOG2_KAPPA (-0.15200309344504997f)   // log2(0.9)
#define KAPPA_T 3.73302e-24f                 // 0.9^512

typedef __attribute__((ext_vector_type(8))) short bf16x8;
typedef __attribute__((ext_vector_type(4))) float f32x4;
typedef __attribute__((ext_vector_type(4))) unsigned u32x4;

__device__ inline unsigned short f2bfu(float x) {
    unsigned u = __builtin_bit_cast(unsigned, x);
    u += 0x7fff + ((u >> 16) & 1);   // RNE
    return (unsigned short)(u >> 16);
}
__device__ inline float bf2f(unsigned short u) {
    return __builtin_bit_cast(float, (unsigned)u << 16);
}
__device__ inline unsigned pack2bf(float lo, float hi) {
    return (unsigned)f2bfu(lo) | ((unsigned)f2bfu(hi) << 16);
}
// packed RNE cvt: lowers to v_cvt_pk_bf16_f32 (1 VALU op / 2 elems).
__device__ inline unsigned cvtpk(float a, float b) {
    __hip_bfloat162 h = __float22bfloat162_rn(float2{a, b});
    unsigned r;
    __builtin_memcpy(&r, &h, sizeof(r));
    return r;
}

// ============ Kernel 1: proj (blocks 0-767) + s_tab (blocks 768-775) ========
// GEMM blocks build their own swizzled Wt in-block from W (L2-resident, 64KB):
// no prep kernel, no inter-launch gap for it. s_tab blocks are independent
// side-cars feeding only the NEXT kernel (no intra-launch dependency - r9).
// Wt LDS layout: byte(d,k) = d*512 + ((2k) ^ ((d&7)<<4)).
__global__ __launch_bounds__(256) void proj_mfma(
    const float* __restrict__ key_in, const float* __restrict__ query,
    const float* __restrict__ value,
    const float* __restrict__ w_q, const float* __restrict__ w_k,
    const float* __restrict__ w_v,
    const unsigned char* __restrict__ raw,
    unsigned short* __restrict__ qp, unsigned short* __restrict__ kp,
    unsigned short* __restrict__ vp, int* __restrict__ s_tab)
{
    __shared__ __align__(16) char Wt[64 * 512];   // 32KB swizzled bf16 image
    const int t   = threadIdx.x;
    const int bid = blockIdx.x;

    if (bid >= 768) {
        // ---- s_tab for batch b: last done timestep <= n, or -1 ----
        const int b    = bid - 768;
        const int lane = t & 63;
        const int w    = t >> 6;
        __shared__ int f;
        __shared__ unsigned long long msk[8];
        if (t == 0) f = 0;
        __syncthreads();
        {   // layout detection: bool(1B) vs int32(4B LE 0/1)
            const uint4* dp = (const uint4*)raw;
            unsigned acc = 0;
#pragma unroll
            for (int i = 0; i < 4; ++i) {
                uint4 v = dp[t + 256 * i];     // 16KB = B_*C_ bytes
                acc |= (v.x | v.y | v.z | v.w) & 0xFFFFFF00u;
            }
            if (acc) f = 1;
        }
        __syncthreads();
        const int stride = f ? 1 : 4;
        const unsigned char* drow = raw + (size_t)b * C_ * stride;
#pragma unroll
        for (int cc = 0; cc < 2; ++cc) {
            const int c = 2 * w + cc;
            const int n = c * 64 + lane;
            unsigned long long m = __ballot(drow[(size_t)(4 * n) * stride] != 0);
            if (lane == 0) msk[c] = m;
        }
        __syncthreads();
#pragma unroll
        for (int cc = 0; cc < 2; ++cc) {
            const int c = 2 * w + cc;
            const int n = c * 64 + lane;
            unsigned long long lowmask =
                (lane == 63) ? ~0ULL : ((1ULL << (lane + 1)) - 1ULL);
            unsigned long long m_le = msk[c] & lowmask;
            int s = -1;
            if (m_le) {
                s = c * 64 + (63 - __builtin_clzll(m_le));
            } else {
                for (int c2 = c - 1; c2 >= 0; --c2)
                    if (msk[c2]) { s = c2 * 64 + (63 - __builtin_clzll(msk[c2])); break; }
            }
            s_tab[b * T_ + n] = s;
        }
        return;
    }

    // ---- GEMM block: mat = bid>>8, b = bid&7 (XCD pin), rb = (bid&255)>>3 --
    const int mat = bid >> 8;
    const float* A; unsigned short* O16; const float* Wg;
    if (mat == 0)      { A = query;  O16 = qp; Wg = w_q; }
    else if (mat == 1) { A = key_in; O16 = kp; Wg = w_k; }
    else               { A = value;  O16 = vp; Wg = w_v; }

    const int b    = bid & 7;
    const int rb   = (bid & 255) >> 3;
    const int row0 = b * C_ + rb * 64;
    const int lane = t & 63;
    const int mt   = t >> 6;
    const int lr   = lane & 15;
    const int lg   = lane >> 4;
    const int swz  = (lr & 7) << 4;

    // in-block W transpose: W[256][64] f32 -> swizzled bf16 Wt (registers only,
    // no tile buffer). Pass p, thread t: kp = k-pair, dq = d-quad.
#pragma unroll
    for (int p = 0; p < 8; ++p) {
        int idx = p * 256 + t;
        int kpair = idx >> 4;           // 0..127
        int dq    = (idx & 15) * 4;     // 0,4,...,60
        f32x4 r0 = *(const f32x4*)&Wg[(size_t)(2 * kpair)     * H_ + dq];
        f32x4 r1 = *(const f32x4*)&Wg[(size_t)(2 * kpair + 1) * H_ + dq];
#pragma unroll
        for (int j = 0; j < 4; ++j) {
            int d = dq + j;
            *(unsigned*)&Wt[(d << 9) + ((4 * kpair) ^ ((d & 7) << 4))] =
                cvtpk(r0[j], r1[j]);
        }
    }

    const float* arow = &A[(size_t)(row0 + mt * 16 + lr) * E_ + lg * 8];

    // prefetch kc=0 A while the transpose drains at the barrier
    f32x4 x0 = *(const f32x4*)(arow);
    f32x4 x1 = *(const f32x4*)(arow + 4);
    __syncthreads();

    f32x4 acc[4] = {};
#pragma unroll
    for (int kc = 0; kc < 8; ++kc) {
        f32x4 n0, n1;
        if (kc < 7) {
            n0 = *(const f32x4*)(arow + (kc + 1) * 32);
            n1 = *(const f32x4*)(arow + (kc + 1) * 32 + 4);
        }
        u32x4 afu = { cvtpk(x0[0], x0[1]), cvtpk(x0[2], x0[3]),
                      cvtpk(x1[0], x1[1]), cvtpk(x1[2], x1[3]) };
        bf16x8 af = __builtin_bit_cast(bf16x8, afu);
#pragma unroll
        for (int nt = 0; nt < 4; ++nt) {
            bf16x8 bfrag = *(const bf16x8*)&Wt[((nt * 16 + lr) << 9) +
                                               ((kc * 64 + lg * 16) ^ swz)];
            acc[nt] = __builtin_amdgcn_mfma_f32_16x16x32_bf16(af, bfrag, acc[nt], 0, 0, 0);
        }
        x0 = n0; x1 = n1;
    }

    // packed bf16 epilogue: lane pair (lr, lr^1) packs adjacent cols into
    // dwords; even lane stores rows 0-1, odd lane rows 2-3 -> dword stores.
    const int odd   = lr & 1;
    const int rbase = row0 + mt * 16 + lg * 4;
#pragma unroll
    for (int nt = 0; nt < 4; ++nt) {
        const int cp = nt * 16 + (lr & ~1);
        float x0_ = acc[nt][0], x1_ = acc[nt][1], x2_ = acc[nt][2], x3_ = acc[nt][3];
        float y0 = __shfl_xor(x0_, 1), y1 = __shfl_xor(x1_, 1);
        float y2 = __shfl_xor(x2_, 1), y3 = __shfl_xor(x3_, 1);
        if (!odd) {
            *(unsigned*)&O16[(size_t)(rbase + 0) * H_ + cp] = pack2bf(x0_, y0);
            *(unsigned*)&O16[(size_t)(rbase + 1) * H_ + cp] = pack2bf(x1_, y1);
        } else {
            *(unsigned*)&O16[(size_t)(rbase + 2) * H_ + cp] = pack2bf(y2, x2_);
            *(unsigned*)&O16[(size_t)(rbase + 3) * H_ + cp] = pack2bf(y3, x3_);
        }
    }
}

// ============ Kernel 2: out0 (blocks 0-1023) + next_h (1024-1151) ===========
__global__ __launch_bounds__(256) void out_kernel(
    const unsigned short* __restrict__ qp, const unsigned short* __restrict__ kp,
    const unsigned short* __restrict__ vp, const float* __restrict__ hs,
    const int* __restrict__ s_tab,
    float* __restrict__ out0, float* __restrict__ outh)
{
    const int t    = threadIdx.x;
    const int lane = t & 63;
    const int w    = t >> 6;
    const int bid  = blockIdx.x;

    if (bid < 1024) {
        const int b = bid & 7;
        const int n = (bid >> 3) * 4 + w;
        const int a = lane >> 4;
        const int g = lane & 15;

        const int st = s_tab[b * T_ + n];
        const int s  = (st < 0) ? 0 : st;

        const unsigned short* kb = kp + (size_t)b * C_ * H_;
        const unsigned short* vb = vp + (size_t)b * C_ * H_;
        ushort4 qu = *(const ushort4*)&qp[((size_t)b * C_ + 4 * n + a) * H_ + 4 * g];
        f32x4 q4 = { bf2f(qu.x), bf2f(qu.y), bf2f(qu.z), bf2f(qu.w) };

        f32x4 acc = {};
        // diagonal timestep: decay 1, causal mask ma <= a
#pragma unroll
        for (int ma = 0; ma < NA; ++ma) {
            const int m = 4 * n + ma;
            ushort4 ku = *(const ushort4*)&kb[(size_t)m * H_ + 4 * g];
            float p = q4[0] * bf2f(ku.x) + q4[1] * bf2f(ku.y)
                    + q4[2] * bf2f(ku.z) + q4[3] * bf2f(ku.w);
            p += __shfl_xor(p, 1); p += __shfl_xor(p, 2);
            p += __shfl_xor(p, 4); p += __shfl_xor(p, 8);
            if (ma <= a) {
                ushort4 vu = *(const ushort4*)&vb[(size_t)m * H_ + 4 * g];
                acc[0] += p * bf2f(vu.x); acc[1] += p * bf2f(vu.y);
                acc[2] += p * bf2f(vu.z); acc[3] += p * bf2f(vu.w);
            }
        }
        // earlier timesteps in segment
        float decay = KAPPA;
        for (int mt = n - 1; mt >= s; --mt) {
#pragma unroll
            for (int ma = 0; ma < NA; ++ma) {
                const int m = 4 * mt + ma;
                ushort4 ku = *(const ushort4*)&kb[(size_t)m * H_ + 4 * g];
                float p = q4[0] * bf2f(ku.x) + q4[1] * bf2f(ku.y)
                        + q4[2] * bf2f(ku.z) + q4[3] * bf2f(ku.w);
                p += __shfl_xor(p, 1); p += __shfl_xor(p, 2);
                p += __shfl_xor(p, 4); p += __shfl_xor(p, 8);
                p *= decay;
                ushort4 vu = *(const ushort4*)&vb[(size_t)m * H_ + 4 * g];
                acc[0] += p * bf2f(vu.x); acc[1] += p * bf2f(vu.y);
                acc[2] += p * bf2f(vu.z); acc[3] += p * bf2f(vu.w);
            }
            decay *= KAPPA;
        }
        // cross term (xi != 0 iff no done in [0, n] <=> st < 0)
        if (st < 0) {
            const float xi = exp2f(LOG2_KAPPA * (float)(n + 1));
            const float* hsb = hs + (size_t)b * H_ * H_;
            f32x4 cacc = {};
#pragma unroll
            for (int h = 0; h < H_; ++h) {
                float qh = __shfl(q4[h & 3], (a << 4) + (h >> 2));
                f32x4 h4 = *(const f32x4*)&hsb[h * H_ + 4 * g];
                cacc[0] += qh * h4[0]; cacc[1] += qh * h4[1];
                cacc[2] += qh * h4[2]; cacc[3] += qh * h4[3];
            }
            acc[0] += xi * cacc[0]; acc[1] += xi * cacc[1];
            acc[2] += xi * cacc[2]; acc[3] += xi * cacc[3];
        }
        *(f32x4*)&out0[((size_t)b * C_ + 4 * n + a) * H_ + 4 * g] = acc;
    } else {
        const int j = bid - 1024;            // [0,128)
        const int b = j & 7;
        const int h = (j >> 3) * 4 + w;      // [0,64)
        const int d = lane;

        const int st = s_tab[b * T_ + (T_ - 1)];
        const int s  = (st < 0) ? 0 : st;

        const unsigned short* kb = kp + (size_t)b * C_ * H_;
        const unsigned short* vb = vp + (size_t)b * C_ * H_;
        float acc = 0.f, wdec = 1.f;
        for (int mt = T_ - 1; mt >= s; --mt) {
#pragma unroll
            for (int ma = 0; ma < NA; ++ma) {
                const int m = 4 * mt + ma;
                acc += wdec * bf2f(kb[(size_t)m * H_ + h]) *
                              bf2f(vb[(size_t)m * H_ + d]);
            }
            wdec *= KAPPA;
        }
        if (st < 0)
            acc += hs[((size_t)b * H_ + h) * H_ + d] * KAPPA_T;
        outh[((size_t)b * H_ + h) * H_ + d] = acc;
    }
}

extern "C" void kernel_launch(void* const* d_in, const int* in_sizes, int n_in,
                              void* d_out, int out_size, void* d_ws, size_t ws_size,
                              hipStream_t stream)
{
    const float* key_in = (const float*)d_in[0];
    const float* query  = (const float*)d_in[1];
    const float* value  = (const float*)d_in[2];
    const float* hstate = (const float*)d_in[3];
    const unsigned char* dones = (const unsigned char*)d_in[4];
    const float* w_q = (const float*)d_in[5];
    const float* w_k = (const float*)d_in[6];
    const float* w_v = (const float*)d_in[7];

    unsigned short* qp = (unsigned short*)d_ws;
    unsigned short* kp = qp + (size_t)B_ * C_ * H_;
    unsigned short* vp = kp + (size_t)B_ * C_ * H_;
    int*         s_tab = (int*)(vp + (size_t)B_ * C_ * H_);

    proj_mfma<<<776, 256, 0, stream>>>(key_in, query, value,
                                       w_q, w_k, w_v, dones,
                                       qp, kp, vp, s_tab);
    out_kernel<<<1024 + 128, 256, 0, stream>>>(
        qp, kp, vp, hstate, s_tab,
        (float*)d_out, (float*)d_out + (size_t)B_ * C_ * H_);
}